// Round 15
// baseline (291.446 us; speedup 1.0000x reference)
//
#include <hip/hip_runtime.h>
#include <hip/hip_bf16.h>

// Problem constants (from reference)
#define NN      50000
#define EE      800000
#define EP      (EE + NN)      // edges + self loops
#define F_IN    128
#define HID     64
#define HEADS   4
#define NCLS    40
#define SLOPE   0.2f

#define NB_SCAN ((NN + 1023) / 1024)   // 49 blocks of 1024 elements

typedef _Float16 half8v __attribute__((ext_vector_type(8)));
typedef _Float16 half4v __attribute__((ext_vector_type(4)));
typedef _Float16 half2v __attribute__((ext_vector_type(2)));
typedef float    f32x4  __attribute__((ext_vector_type(4)));
typedef float    f32x2  __attribute__((ext_vector_type(2)));
typedef unsigned int  uint;
typedef unsigned short ushort;

__device__ __forceinline__ float lrelu_exp(float e) {
    return __expf(fmaxf(e, SLOPE * e));   // max(e,0.2e) == leaky_relu
}

// ---------------- CSR build ----------------

__global__ __launch_bounds__(256) void hist_kernel(const int* __restrict__ ei, int* deg) {
    int e = blockIdx.x * 256 + threadIdx.x;
    if (e < EE) atomicAdd(&deg[ei[EE + e]], 1);   // dst = ei[1][e]
}

// multi-block exclusive scan over (deg+1) — the +1 is the self-loop
__global__ __launch_bounds__(256) void scan_blocks(const int* __restrict__ deg,
                                                   int* __restrict__ off,
                                                   int* __restrict__ bsum) {
    __shared__ int wsum[4];
    const int bid = blockIdx.x, t = threadIdx.x;
    const int base = bid * 1024 + t * 4;
    int d0 = 0, d1 = 0, d2 = 0, d3 = 0;
    if (base + 3 < NN) {
        int4 v = *(const int4*)(deg + base);
        d0 = v.x + 1; d1 = v.y + 1; d2 = v.z + 1; d3 = v.w + 1;
    } else {
        if (base + 0 < NN) d0 = deg[base + 0] + 1;
        if (base + 1 < NN) d1 = deg[base + 1] + 1;
        if (base + 2 < NN) d2 = deg[base + 2] + 1;
        if (base + 3 < NN) d3 = deg[base + 3] + 1;
    }
    const int tsum = d0 + d1 + d2 + d3;
    const int lane = t & 63, wv = t >> 6;
    int inc = tsum;
#pragma unroll
    for (int o = 1; o < 64; o <<= 1) {
        int u = __shfl_up(inc, o);
        if (lane >= o) inc += u;
    }
    if (lane == 63) wsum[wv] = inc;
    __syncthreads();
    int woff = 0;
#pragma unroll
    for (int w = 0; w < 4; ++w) woff += (w < wv) ? wsum[w] : 0;
    const int excl = woff + inc - tsum;
    if (base + 3 < NN) {
        int4 o4;
        o4.x = excl;
        o4.y = excl + d0;
        o4.z = excl + d0 + d1;
        o4.w = excl + d0 + d1 + d2;
        *(int4*)(off + base) = o4;
    } else {
        if (base + 0 < NN) off[base + 0] = excl;
        if (base + 1 < NN) off[base + 1] = excl + d0;
        if (base + 2 < NN) off[base + 2] = excl + d0 + d1;
        if (base + 3 < NN) off[base + 3] = excl + d0 + d1 + d2;
    }
    if (t == 255) bsum[bid] = woff + inc;
}

__global__ __launch_bounds__(64) void scan_spine(int* __restrict__ bsum,
                                                 int* __restrict__ off) {
    const int lane = threadIdx.x;
    int v = (lane < NB_SCAN) ? bsum[lane] : 0;
    int inc = v;
#pragma unroll
    for (int o = 1; o < 64; o <<= 1) {
        int u = __shfl_up(inc, o);
        if (lane >= o) inc += u;
    }
    if (lane < NB_SCAN) bsum[lane] = inc - v;
    if (lane == 63) off[NN] = inc;
}

__global__ __launch_bounds__(256) void scan_apply(const int* __restrict__ bsum,
                                                  int* __restrict__ off,
                                                  int* __restrict__ cur) {
    const int bid = blockIdx.x, t = threadIdx.x;
    const int boff = bsum[bid];
    const int base = bid * 1024 + t * 4;
    if (base + 3 < NN) {
        int4 v = *(const int4*)(off + base);
        v.x += boff; v.y += boff; v.z += boff; v.w += boff;
        *(int4*)(off + base) = v;
        *(int4*)(cur + base) = v;
    } else {
        for (int i = 0; i < 4; ++i)
            if (base + i < NN) {
                int v = off[base + i] + boff;
                off[base + i] = v;
                cur[base + i] = v;
            }
    }
}

// single random 2B write per edge (node ids < 65536)
__global__ __launch_bounds__(256) void scatter_kernel(const int* __restrict__ ei,
                                                      int* __restrict__ cur,
                                                      ushort* __restrict__ csr) {
    int i = blockIdx.x * 256 + threadIdx.x;
    if (i >= EP) return;
    int s, d;
    if (i < NN) { s = i; d = i; }           // self loop
    else { int e = i - NN; s = ei[e]; d = ei[EE + e]; }
    int pos = atomicAdd(&cur[d], 1);
    csr[pos] = (ushort)s;
}

// ---------------- weight prep ----------------

// va[v][k] = sum_c W1[k, 64*(v&3)+c] * a1[(v&3)][c], v<4: src, v>=4: dst
__global__ __launch_bounds__(256) void prep_va(const float* __restrict__ W1,
                                               const float* __restrict__ a_src1,
                                               const float* __restrict__ a_dst1,
                                               float* __restrict__ va) {
    int idx = blockIdx.x * 256 + threadIdx.x;
    if (idx >= 1024) return;
    int v = idx >> 7, k = idx & 127, h = v & 3;
    const float* a = (v < 4) ? a_src1 : a_dst1;
    float s = 0.f;
    for (int c = 0; c < 64; ++c)
        s = fmaf(W1[(size_t)k * 256 + h * 64 + c], a[h * 64 + c], s);
    va[v * 128 + k] = s;
}

// W1stack[kap = h*128+kx][c] = W1[kx][64h+c], sigma-packed fp16
__global__ __launch_bounds__(256) void prep_g1b(const float* __restrict__ W1,
                                                _Float16* __restrict__ Bg) {
    int idx = blockIdx.x * 256 + threadIdx.x;
    if (idx >= 4096) return;
    int l = idx & 63, kk = (idx >> 6) & 15, nb = idx >> 10;
    int c = 16 * nb + (l & 15);
    half8v v;
#pragma unroll
    for (int jj = 0; jj < 8; ++jj) {
        int kap = 32 * kk + 8 * (l >> 4) + jj;
        int kx = kap & 127, hh = kap >> 7;
        v[jj] = (_Float16)W1[(size_t)kx * 256 + hh * 64 + c];
    }
    *(half8v*)(Bg + (size_t)idx * 8) = v;
}

// layer-2 folded logit vectors
__global__ __launch_bounds__(256) void prep_v(const float* __restrict__ W2,
                                              const float* __restrict__ a_src2,
                                              const float* __restrict__ a_dst2,
                                              float* __restrict__ vs,
                                              float* __restrict__ vd) {
    int idx = threadIdx.x;
    int h = idx >> 6, k = idx & 63;
    float s = 0.f, d = 0.f;
    for (int c = 0; c < NCLS; ++c) {
        float w = W2[(size_t)k * 160 + h * 40 + c];
        s = fmaf(w, a_src2[h * 40 + c], s);
        d = fmaf(w, a_dst2[h * 40 + c], d);
    }
    vs[idx] = s; vd[idx] = d;
}

// W2 fragment-packed
__global__ __launch_bounds__(256) void prep_w2(const float* __restrict__ W2,
                                               _Float16* __restrict__ Bp) {
    int idx = blockIdx.x * 256 + threadIdx.x;
    if (idx >= 1536) return;
    int l = idx & 63, kk = (idx >> 6) & 7, n = idx >> 9;
    int c = 16 * n + (l & 15);
    half8v v;
#pragma unroll
    for (int j = 0; j < 8; ++j) {
        int kap = 32 * kk + 8 * (l >> 4) + j;
        float w = (c < NCLS) ? W2[(size_t)(kap & 63) * 160 + (kap >> 6) * 40 + c] : 0.f;
        v[j] = (_Float16)w;
    }
    *(half8v*)(Bp + (size_t)idx * 8) = v;
}

// ---------------- x -> fp16 table + alpha1 logits (x . va) ----------------
__global__ __launch_bounds__(256)
void xprep_kernel(const float* __restrict__ x, const float* __restrict__ va,
                  _Float16* __restrict__ xh, float* __restrict__ as1,
                  float* __restrict__ ad1) {
    int n = (blockIdx.x * 256 + threadIdx.x) >> 6;
    if (n >= NN) return;
    int lane = threadIdx.x & 63;
    float2 xv = *(const float2*)(x + (size_t)n * 128 + lane * 2);
    half2v hx; hx.x = (_Float16)xv.x; hx.y = (_Float16)xv.y;
    *(half2v*)((char*)xh + ((size_t)n << 8) + lane * 4) = hx;
    float p[8];
#pragma unroll
    for (int v = 0; v < 8; ++v) {
        float2 c = *(const float2*)(va + v * 128 + lane * 2);
        p[v] = xv.x * c.x + xv.y * c.y;
    }
#pragma unroll
    for (int m = 1; m < 64; m <<= 1)
#pragma unroll
        for (int v = 0; v < 8; ++v) p[v] += __shfl_xor(p[v], m);
    if (lane == 0) {
        float4 s; s.x = p[0]; s.y = p[1]; s.z = p[2]; s.w = p[3];
        float4 d; d.x = p[4]; d.y = p[5]; d.z = p[6]; d.w = p[7];
        *(float4*)(as1 + n * 4) = s;
        *(float4*)(ad1 + n * 4) = d;
    }
}

// ---------------- layer-1 aggregation of RAW x (fp16) ----------------
// wave per node. lane = (halfSel = lane>>5, lq = lane&31): lane loads half4v
// (channels 4lq..4lq+3) of edge j+halfSel / j+2+halfSel -> 2 gather insts per
// 4 edges. Weight lanes 0..15 compute w(eC,hC); consumers shfl. Final
// shfl_xor(32) combine; each half stores 2 heads.
__global__ __launch_bounds__(256)
void agg1x_kernel(const _Float16* __restrict__ xh, const float* __restrict__ as1,
                  const float* __restrict__ ad1, const int* __restrict__ off,
                  const ushort* __restrict__ csr, _Float16* __restrict__ G1) {
    int n = (blockIdx.x * 256 + threadIdx.x) >> 6;
    if (n >= NN) return;
    const int lane = threadIdx.x & 63;
    const int halfSel = lane >> 5, lq = lane & 31;
    const int hC = (lane >> 2) & 3, eC = lane & 3;
    const float advC = ad1[n * 4 + hC];
    // loop-invariant per-head dst logits (for tail)
    float adv0 = __shfl(advC, 0), adv1 = __shfl(advC, 4);
    float adv2 = __shfl(advC, 8), adv3 = __shfl(advC, 12);
    const char* xb = (const char*)xh;
    const uint cb = (uint)lq * 8u;
    int e0 = off[n], e1 = off[n + 1];
    f32x2 acc[4][2];
#pragma unroll
    for (int h = 0; h < 4; ++h) { acc[h][0] = (f32x2){0.f, 0.f}; acc[h][1] = (f32x2){0.f, 0.f}; }
    f32x2 d01 = {0.f, 0.f}, d23 = {0.f, 0.f};
    int j = e0;
    for (; j + 4 <= e1; j += 4) {
        int sC = csr[j + eC];
        float wX = lrelu_exp(as1[sC * 4 + hC] + advC);
        int sA = csr[j + halfSel];          // edge halfSel of pair 1
        int sB = csr[j + 2 + halfSel];      // edge halfSel of pair 2
        half4v xa = *(const half4v*)(xb + (((uint)sA << 8) + cb));
        half4v xv2 = *(const half4v*)(xb + (((uint)sB << 8) + cb));
        // weights for this lane's two edges, all 4 heads
        float wA0 = __shfl(wX, 0 + halfSel),  wA1 = __shfl(wX, 4 + halfSel);
        float wA2 = __shfl(wX, 8 + halfSel),  wA3 = __shfl(wX, 12 + halfSel);
        float wB0 = __shfl(wX, 2 + halfSel),  wB1 = __shfl(wX, 6 + halfSel);
        float wB2 = __shfl(wX, 10 + halfSel), wB3 = __shfl(wX, 14 + halfSel);
        f32x2 fa0 = {(float)xa.x, (float)xa.y},  fa1 = {(float)xa.z, (float)xa.w};
        f32x2 fb0 = {(float)xv2.x, (float)xv2.y}, fb1 = {(float)xv2.z, (float)xv2.w};
        acc[0][0] = __builtin_elementwise_fma((f32x2){wA0, wA0}, fa0, acc[0][0]);
        acc[0][1] = __builtin_elementwise_fma((f32x2){wA0, wA0}, fa1, acc[0][1]);
        acc[1][0] = __builtin_elementwise_fma((f32x2){wA1, wA1}, fa0, acc[1][0]);
        acc[1][1] = __builtin_elementwise_fma((f32x2){wA1, wA1}, fa1, acc[1][1]);
        acc[2][0] = __builtin_elementwise_fma((f32x2){wA2, wA2}, fa0, acc[2][0]);
        acc[2][1] = __builtin_elementwise_fma((f32x2){wA2, wA2}, fa1, acc[2][1]);
        acc[3][0] = __builtin_elementwise_fma((f32x2){wA3, wA3}, fa0, acc[3][0]);
        acc[3][1] = __builtin_elementwise_fma((f32x2){wA3, wA3}, fa1, acc[3][1]);
        acc[0][0] = __builtin_elementwise_fma((f32x2){wB0, wB0}, fb0, acc[0][0]);
        acc[0][1] = __builtin_elementwise_fma((f32x2){wB0, wB0}, fb1, acc[0][1]);
        acc[1][0] = __builtin_elementwise_fma((f32x2){wB1, wB1}, fb0, acc[1][0]);
        acc[1][1] = __builtin_elementwise_fma((f32x2){wB1, wB1}, fb1, acc[1][1]);
        acc[2][0] = __builtin_elementwise_fma((f32x2){wB2, wB2}, fb0, acc[2][0]);
        acc[2][1] = __builtin_elementwise_fma((f32x2){wB2, wB2}, fb1, acc[2][1]);
        acc[3][0] = __builtin_elementwise_fma((f32x2){wB3, wB3}, fb0, acc[3][0]);
        acc[3][1] = __builtin_elementwise_fma((f32x2){wB3, wB3}, fb1, acc[3][1]);
        d01 += (f32x2){wA0 + wB0, wA1 + wB1};
        d23 += (f32x2){wA2 + wB2, wA3 + wB3};
    }
    for (; j < e1; ++j) {
        int s = csr[j];
        half4v xa = *(const half4v*)(xb + (((uint)s << 8) + cb));
        float4 av = *(const float4*)(as1 + s * 4);
        float gate = (halfSel == 0) ? 1.f : 0.f;   // count each edge once across halves
        float w0 = gate * lrelu_exp(av.x + adv0);
        float w1 = gate * lrelu_exp(av.y + adv1);
        float w2 = gate * lrelu_exp(av.z + adv2);
        float w3 = gate * lrelu_exp(av.w + adv3);
        f32x2 f0 = {(float)xa.x, (float)xa.y}, f1 = {(float)xa.z, (float)xa.w};
        acc[0][0] = __builtin_elementwise_fma((f32x2){w0, w0}, f0, acc[0][0]);
        acc[0][1] = __builtin_elementwise_fma((f32x2){w0, w0}, f1, acc[0][1]);
        acc[1][0] = __builtin_elementwise_fma((f32x2){w1, w1}, f0, acc[1][0]);
        acc[1][1] = __builtin_elementwise_fma((f32x2){w1, w1}, f1, acc[1][1]);
        acc[2][0] = __builtin_elementwise_fma((f32x2){w2, w2}, f0, acc[2][0]);
        acc[2][1] = __builtin_elementwise_fma((f32x2){w2, w2}, f1, acc[2][1]);
        acc[3][0] = __builtin_elementwise_fma((f32x2){w3, w3}, f0, acc[3][0]);
        acc[3][1] = __builtin_elementwise_fma((f32x2){w3, w3}, f1, acc[3][1]);
        d01 += (f32x2){w0, w1}; d23 += (f32x2){w2, w3};
    }
    // combine halves (lanes l and l+32 hold same channels, different edges)
#pragma unroll
    for (int h = 0; h < 4; ++h)
#pragma unroll
        for (int p0 = 0; p0 < 2; ++p0) {
            acc[h][p0][0] += __shfl_xor(acc[h][p0][0], 32);
            acc[h][p0][1] += __shfl_xor(acc[h][p0][1], 32);
        }
    d01[0] += __shfl_xor(d01[0], 32); d01[1] += __shfl_xor(d01[1], 32);
    d23[0] += __shfl_xor(d23[0], 32); d23[1] += __shfl_xor(d23[1], 32);
    float iv[4];
    iv[0] = 1.f / (d01[0] + 1e-16f);
    iv[1] = 1.f / (d01[1] + 1e-16f);
    iv[2] = 1.f / (d23[0] + 1e-16f);
    iv[3] = 1.f / (d23[1] + 1e-16f);
    // each half stores 2 heads (both halves hold identical combined sums)
    char* gb = (char*)G1 + ((size_t)n << 10);
#pragma unroll
    for (int hh = 0; hh < 2; ++hh) {
        int h = halfSel * 2 + hh;
        float s = iv[h];
        half4v o;
        o.x = (_Float16)(acc[h][0][0] * s); o.y = (_Float16)(acc[h][0][1] * s);
        o.z = (_Float16)(acc[h][1][0] * s); o.w = (_Float16)(acc[h][1][1] * s);
        *(half4v*)(gb + (uint)h * 256u + cb) = o;
    }
}

// ---------------- gemm_g1: h1o[N,64] = relu(0.25*G1[N,512]@W1stack + b1); + logits ----------------
__global__ __launch_bounds__(256)
void gemm_g1(const _Float16* __restrict__ G1, const _Float16* __restrict__ Bg,
             const float* __restrict__ b1, const float* __restrict__ vs,
             const float* __restrict__ vd, _Float16* __restrict__ h1of,
             float* __restrict__ as2, float* __restrict__ ad2, int M) {
    __shared__ _Float16 Al[64 * 512];   // 64 KB
    const int t    = threadIdx.x;
    const int row0 = blockIdx.x * 64;

#pragma unroll
    for (int i = 0; i < 16; ++i) {
        int chunk = i * 256 + t;
        int r = chunk >> 6, c8 = (chunk & 63) * 8;
        int rg = row0 + r; if (rg >= M) rg = M - 1;
        half8v v = *(const half8v*)(G1 + ((size_t)rg << 9) + c8);
        int byte = (r * 1024 + c8 * 2) ^ ((r & 7) << 4);
        *(half8v*)((char*)Al + byte) = v;
    }
    __syncthreads();

    const int lane = t & 63, w = t >> 6;
    const int g = lane >> 4, cc = lane & 15;

    half8v a[16];
#pragma unroll
    for (int kk = 0; kk < 16; ++kk) {
        int r = 16 * w + cc;
        int byte = (r * 1024 + (32 * kk + 8 * g) * 2) ^ ((r & 7) << 4);
        a[kk] = *(const half8v*)((const char*)Al + byte);
    }

    f32x4 acc[4];
#pragma unroll
    for (int nb = 0; nb < 4; ++nb)
#pragma unroll
        for (int i = 0; i < 4; ++i) acc[nb][i] = 0.f;

#pragma unroll
    for (int nb = 0; nb < 4; ++nb)
#pragma unroll
        for (int kk = 0; kk < 16; ++kk) {
            half8v b = *(const half8v*)(Bg + ((size_t)(nb * 16 + kk) * 64 + lane) * 8);
            acc[nb] = __builtin_amdgcn_mfma_f32_16x16x32_f16(a[kk], b, acc[nb], 0, 0, 0);
        }

#pragma unroll
    for (int i = 0; i < 4; ++i) {
        int r = row0 + 16 * w + 4 * g + i;
        float o[4];
#pragma unroll
        for (int nb = 0; nb < 4; ++nb)
            o[nb] = fmaxf(0.25f * acc[nb][i] + b1[16 * nb + cc], 0.f);
        bool ok = (r < M) && !(cc & 1);
#pragma unroll
        for (int nb = 0; nb < 4; ++nb) {
            float v1 = __shfl_xor(o[nb], 1);
            if (ok) {
                half2v h2; h2.x = (_Float16)o[nb]; h2.y = (_Float16)v1;
                *(half2v*)(h1of + (size_t)r * 64 + 16 * nb + cc) = h2;
            }
        }
#pragma unroll
        for (int h = 0; h < 4; ++h) {
            float s = 0.f, d = 0.f;
#pragma unroll
            for (int nb = 0; nb < 4; ++nb) {
                s = fmaf(o[nb], vs[h * 64 + 16 * nb + cc], s);
                d = fmaf(o[nb], vd[h * 64 + 16 * nb + cc], d);
            }
#pragma unroll
            for (int m = 1; m <= 8; m <<= 1) {
                s += __shfl_xor(s, m);
                d += __shfl_xor(d, m);
            }
            if (cc == 0 && r < M) { as2[r * 4 + h] = s; ad2[r * 4 + h] = d; }
        }
    }
}

// ---------------- layer-2 aggregation: 4 edges per gather instruction ----------------
// lane = (eSel = lane>>4, q = lane&15): lane loads half4v (channels 4q..4q+3)
// of edge j+eSel -> ONE gather inst per 4 edges. 2-level shfl combine.
__global__ __launch_bounds__(256)
void agg2_kernel(const _Float16* __restrict__ h1of, const float* __restrict__ as2,
                 const float* __restrict__ ad2, const int* __restrict__ off,
                 const ushort* __restrict__ csr, _Float16* __restrict__ g2h) {
    int n = (blockIdx.x * 256 + threadIdx.x) >> 6;
    if (n >= NN) return;
    const int lane = threadIdx.x & 63;
    const int eSel = lane >> 4, q = lane & 15;
    const int hC = (lane >> 2) & 3, eC = lane & 3;
    const float advC = ad2[n * 4 + hC];
    float adv0 = __shfl(advC, 0), adv1 = __shfl(advC, 4);
    float adv2 = __shfl(advC, 8), adv3 = __shfl(advC, 12);
    const char* hb = (const char*)h1of;
    const uint cb = (uint)q * 8u;
    int e0 = off[n], e1 = off[n + 1];
    f32x2 acc[4][2];
#pragma unroll
    for (int h = 0; h < 4; ++h) { acc[h][0] = (f32x2){0.f, 0.f}; acc[h][1] = (f32x2){0.f, 0.f}; }
    f32x2 d01 = {0.f, 0.f}, d23 = {0.f, 0.f};
    int j = e0;
    for (; j + 4 <= e1; j += 4) {
        int sC = csr[j + eC];
        float wX = lrelu_exp(as2[sC * 4 + hC] + advC);
        int sE = csr[j + eSel];
        half4v v = *(const half4v*)(hb + (((uint)sE << 7) + cb));
        float w0 = __shfl(wX, 0 + eSel);
        float w1 = __shfl(wX, 4 + eSel);
        float w2 = __shfl(wX, 8 + eSel);
        float w3 = __shfl(wX, 12 + eSel);
        f32x2 f0 = {(float)v.x, (float)v.y}, f1 = {(float)v.z, (float)v.w};
        acc[0][0] = __builtin_elementwise_fma((f32x2){w0, w0}, f0, acc[0][0]);
        acc[0][1] = __builtin_elementwise_fma((f32x2){w0, w0}, f1, acc[0][1]);
        acc[1][0] = __builtin_elementwise_fma((f32x2){w1, w1}, f0, acc[1][0]);
        acc[1][1] = __builtin_elementwise_fma((f32x2){w1, w1}, f1, acc[1][1]);
        acc[2][0] = __builtin_elementwise_fma((f32x2){w2, w2}, f0, acc[2][0]);
        acc[2][1] = __builtin_elementwise_fma((f32x2){w2, w2}, f1, acc[2][1]);
        acc[3][0] = __builtin_elementwise_fma((f32x2){w3, w3}, f0, acc[3][0]);
        acc[3][1] = __builtin_elementwise_fma((f32x2){w3, w3}, f1, acc[3][1]);
        d01 += (f32x2){w0, w1}; d23 += (f32x2){w2, w3};
    }
    for (; j < e1; ++j) {
        int s = csr[j];
        half4v v = *(const half4v*)(hb + (((uint)s << 7) + cb));
        float4 av = *(const float4*)(as2 + s * 4);
        float gate = (eSel == 0) ? 1.f : 0.f;
        float w0 = gate * lrelu_exp(av.x + adv0);
        float w1 = gate * lrelu_exp(av.y + adv1);
        float w2 = gate * lrelu_exp(av.z + adv2);
        float w3 = gate * lrelu_exp(av.w + adv3);
        f32x2 f0 = {(float)v.x, (float)v.y}, f1 = {(float)v.z, (float)v.w};
        acc[0][0] = __builtin_elementwise_fma((f32x2){w0, w0}, f0, acc[0][0]);
        acc[0][1] = __builtin_elementwise_fma((f32x2){w0, w0}, f1, acc[0][1]);
        acc[1][0] = __builtin_elementwise_fma((f32x2){w1, w1}, f0, acc[1][0]);
        acc[1][1] = __builtin_elementwise_fma((f32x2){w1, w1}, f1, acc[1][1]);
        acc[2][0] = __builtin_elementwise_fma((f32x2){w2, w2}, f0, acc[2][0]);
        acc[2][1] = __builtin_elementwise_fma((f32x2){w2, w2}, f1, acc[2][1]);
        acc[3][0] = __builtin_elementwise_fma((f32x2){w3, w3}, f0, acc[3][0]);
        acc[3][1] = __builtin_elementwise_fma((f32x2){w3, w3}, f1, acc[3][1]);
        d01 += (f32x2){w0, w1}; d23 += (f32x2){w2, w3};
    }
    // combine the 4 edge groups (same channels at lanes ±16, ±32)
#pragma unroll
    for (int m = 16; m <= 32; m <<= 1) {
#pragma unroll
        for (int h = 0; h < 4; ++h)
#pragma unroll
            for (int p0 = 0; p0 < 2; ++p0) {
                acc[h][p0][0] += __shfl_xor(acc[h][p0][0], m);
                acc[h][p0][1] += __shfl_xor(acc[h][p0][1], m);
            }
        d01[0] += __shfl_xor(d01[0], m); d01[1] += __shfl_xor(d01[1], m);
        d23[0] += __shfl_xor(d23[0], m); d23[1] += __shfl_xor(d23[1], m);
    }
    float iv[4];
    iv[0] = 1.f / (d01[0] + 1e-16f);
    iv[1] = 1.f / (d01[1] + 1e-16f);
    iv[2] = 1.f / (d23[0] + 1e-16f);
    iv[3] = 1.f / (d23[1] + 1e-16f);
    // lane (eSel, q) stores head eSel's channels 4q..4q+3 (all lanes hold full sums)
    float s = iv[eSel];
    half4v g;
    g.x = (_Float16)(acc[eSel][0][0] * s); g.y = (_Float16)(acc[eSel][0][1] * s);
    g.z = (_Float16)(acc[eSel][1][0] * s); g.w = (_Float16)(acc[eSel][1][1] * s);
    *(half4v*)((char*)g2h + ((size_t)n << 9) + (uint)eSel * 128u + cb) = g;
}

// ---------------- output GEMM: out = 0.25*g2[N,256]@Bp + b2 ----------------
__global__ __launch_bounds__(256)
void gemm_out(const _Float16* __restrict__ g2h, const _Float16* __restrict__ Bp,
              const float* __restrict__ b2, float* __restrict__ out, int M) {
    __shared__ _Float16 Al[128 * 256];   // 64 KB
    const int t    = threadIdx.x;
    const int row0 = blockIdx.x * 128;

#pragma unroll
    for (int i = 0; i < 16; ++i) {
        int chunk = i * 256 + t;
        int r = chunk >> 5, c = (chunk & 31) * 8;
        int rg = row0 + r; if (rg >= M) rg = M - 1;
        half8v v = *(const half8v*)(g2h + (size_t)rg * 256 + c);
        int byte = (r * 512 + c * 2) ^ ((r & 7) << 4);
        *(half8v*)((char*)Al + byte) = v;
    }
    __syncthreads();

    const int lane = t & 63, w = t >> 6;
    const int g = lane >> 4, cc = lane & 15;

    half8v a[2][8];
#pragma unroll
    for (int m = 0; m < 2; ++m)
#pragma unroll
        for (int kk = 0; kk < 8; ++kk) {
            int r = 32 * w + 16 * m + cc;
            int byte = (r * 512 + (32 * kk + 8 * g) * 2) ^ ((r & 7) << 4);
            a[m][kk] = *(const half8v*)((const char*)Al + byte);
        }

    f32x4 acc[2][3];
#pragma unroll
    for (int m = 0; m < 2; ++m)
#pragma unroll
        for (int n = 0; n < 3; ++n)
#pragma unroll
            for (int i = 0; i < 4; ++i) acc[m][n][i] = 0.f;

#pragma unroll
    for (int n = 0; n < 3; ++n)
#pragma unroll
        for (int kk = 0; kk < 8; ++kk) {
            half8v b = *(const half8v*)(Bp + ((size_t)(n * 8 + kk) * 64 + lane) * 8);
            acc[0][n] = __builtin_amdgcn_mfma_f32_16x16x32_f16(a[0][kk], b, acc[0][n], 0, 0, 0);
            acc[1][n] = __builtin_amdgcn_mfma_f32_16x16x32_f16(a[1][kk], b, acc[1][n], 0, 0, 0);
        }

#pragma unroll
    for (int m = 0; m < 2; ++m)
#pragma unroll
        for (int i = 0; i < 4; ++i) {
            int r = row0 + 32 * w + 16 * m + 4 * g + i;
            if (r < M) {
#pragma unroll
                for (int n = 0; n < 3; ++n) {
                    int c = 16 * n + cc;
                    if (c < NCLS)
                        out[(size_t)r * 40 + c] = 0.25f * acc[m][n][i] + b2[c];
                }
            }
        }
}

// ---------------- launch ----------------

extern "C" void kernel_launch(void* const* d_in, const int* in_sizes, int n_in,
                              void* d_out, int out_size, void* d_ws, size_t ws_size,
                              hipStream_t stream) {
    const float* x      = (const float*)d_in[0];
    const int*   ei     = (const int*)  d_in[1];
    const float* W1     = (const float*)d_in[2];
    const float* a_src1 = (const float*)d_in[3];
    const float* a_dst1 = (const float*)d_in[4];
    const float* b1     = (const float*)d_in[5];
    const float* W2     = (const float*)d_in[6];
    const float* a_src2 = (const float*)d_in[7];
    const float* a_dst2 = (const float*)d_in[8];
    const float* b2     = (const float*)d_in[9];
    float* out = (float*)d_out;

    char* p = (char*)d_ws;
    auto alloc = [&](size_t bytes) {
        void* r = (void*)p;
        p += (bytes + 255) & ~(size_t)255;
        return r;
    };
    int*       deg  = (int*)alloc((size_t)NN * 4);
    int*       off  = (int*)alloc((size_t)(NN + 1) * 4);
    int*       cur  = (int*)alloc((size_t)NN * 4);
    int*       bsum = (int*)alloc((size_t)NB_SCAN * 4);
    ushort*    csr  = (ushort*)alloc((size_t)EP * 2);
    float*     va   = (float*)alloc((size_t)1024 * 4);
    _Float16*  Bg   = (_Float16*)alloc((size_t)4096 * 8 * 2);
    float*     vs   = (float*)alloc((size_t)256 * 4);
    float*     vd   = (float*)alloc((size_t)256 * 4);
    _Float16*  Bp   = (_Float16*)alloc((size_t)1536 * 8 * 2);
    _Float16*  xh   = (_Float16*)alloc((size_t)NN * 128 * 2);   // 12.8 MB gather table
    float*     as1  = (float*)alloc((size_t)NN * 4 * 4);
    float*     ad1  = (float*)alloc((size_t)NN * 4 * 4);
    _Float16*  G1   = (_Float16*)alloc((size_t)NN * 512 * 2);   // 51.2 MB; reused as g2h
    _Float16*  h1of = (_Float16*)alloc((size_t)NN * 64 * 2);    // 6.4 MB gather table
    float*     as2  = (float*)alloc((size_t)NN * 4 * 4);
    float*     ad2  = (float*)alloc((size_t)NN * 4 * 4);
    _Float16*  g2h  = G1;   // G1 dead after gemm_g1

    // CSR over dst (shared by both layers)
    hipMemsetAsync(deg, 0, (size_t)NN * 4, stream);
    hist_kernel<<<(EE + 255) / 256, 256, 0, stream>>>(ei, deg);
    scan_blocks<<<NB_SCAN, 256, 0, stream>>>(deg, off, bsum);
    scan_spine<<<1, 64, 0, stream>>>(bsum, off);
    scan_apply<<<NB_SCAN, 256, 0, stream>>>(bsum, off, cur);
    scatter_kernel<<<(EP + 255) / 256, 256, 0, stream>>>(ei, cur, csr);

    // weight prep
    prep_va<<<4, 256, 0, stream>>>(W1, a_src1, a_dst1, va);
    prep_g1b<<<16, 256, 0, stream>>>(W1, Bg);
    prep_v<<<1, 256, 0, stream>>>(W2, a_src2, a_dst2, vs, vd);
    prep_w2<<<6, 256, 0, stream>>>(W2, Bp);

    // layer 1 (weights fused into aggregation)
    xprep_kernel<<<(NN + 3) / 4, 256, 0, stream>>>(x, va, xh, as1, ad1);
    agg1x_kernel<<<(NN + 3) / 4, 256, 0, stream>>>(xh, as1, ad1, off, csr, G1);
    gemm_g1<<<(NN + 63) / 64, 256, 0, stream>>>(G1, Bg, b1, vs, vd, h1of, as2, ad2, NN);

    // layer 2 (weights fused into aggregation)
    agg2_kernel<<<(NN + 3) / 4, 256, 0, stream>>>(h1of, as2, ad2, off, csr, g2h);
    gemm_out<<<(NN + 127) / 128, 256, 0, stream>>>(g2h, Bp, b2, out, NN);
}

// Round 16
// 270.542 us; speedup vs baseline: 1.0773x; 1.0773x over previous
//
#include <hip/hip_runtime.h>
#include <hip/hip_bf16.h>

// Problem constants (from reference)
#define NN      50000
#define EE      800000
#define EP      (EE + NN)      // edges + self loops
#define F_IN    128
#define HID     64
#define HEADS   4
#define NCLS    40
#define SLOPE   0.2f

#define NB_SCAN ((NN + 1023) / 1024)   // 49 blocks of 1024 elements

typedef _Float16 half8v __attribute__((ext_vector_type(8)));
typedef _Float16 half4v __attribute__((ext_vector_type(4)));
typedef _Float16 half2v __attribute__((ext_vector_type(2)));
typedef float    f32x4  __attribute__((ext_vector_type(4)));
typedef float    f32x2  __attribute__((ext_vector_type(2)));
typedef unsigned int  uint;
typedef unsigned short ushort;

__device__ __forceinline__ float lrelu_exp(float e) {
    return __expf(fmaxf(e, SLOPE * e));   // max(e,0.2e) == leaky_relu
}

// ---------------- CSR build ----------------

__global__ __launch_bounds__(256) void hist_kernel(const int* __restrict__ ei, int* deg) {
    int e = blockIdx.x * 256 + threadIdx.x;
    if (e < EE) atomicAdd(&deg[ei[EE + e]], 1);   // dst = ei[1][e]
}

// multi-block exclusive scan over (deg+1) — the +1 is the self-loop
__global__ __launch_bounds__(256) void scan_blocks(const int* __restrict__ deg,
                                                   int* __restrict__ off,
                                                   int* __restrict__ bsum) {
    __shared__ int wsum[4];
    const int bid = blockIdx.x, t = threadIdx.x;
    const int base = bid * 1024 + t * 4;
    int d0 = 0, d1 = 0, d2 = 0, d3 = 0;
    if (base + 3 < NN) {
        int4 v = *(const int4*)(deg + base);
        d0 = v.x + 1; d1 = v.y + 1; d2 = v.z + 1; d3 = v.w + 1;
    } else {
        if (base + 0 < NN) d0 = deg[base + 0] + 1;
        if (base + 1 < NN) d1 = deg[base + 1] + 1;
        if (base + 2 < NN) d2 = deg[base + 2] + 1;
        if (base + 3 < NN) d3 = deg[base + 3] + 1;
    }
    const int tsum = d0 + d1 + d2 + d3;
    const int lane = t & 63, wv = t >> 6;
    int inc = tsum;
#pragma unroll
    for (int o = 1; o < 64; o <<= 1) {
        int u = __shfl_up(inc, o);
        if (lane >= o) inc += u;
    }
    if (lane == 63) wsum[wv] = inc;
    __syncthreads();
    int woff = 0;
#pragma unroll
    for (int w = 0; w < 4; ++w) woff += (w < wv) ? wsum[w] : 0;
    const int excl = woff + inc - tsum;
    if (base + 3 < NN) {
        int4 o4;
        o4.x = excl;
        o4.y = excl + d0;
        o4.z = excl + d0 + d1;
        o4.w = excl + d0 + d1 + d2;
        *(int4*)(off + base) = o4;
    } else {
        if (base + 0 < NN) off[base + 0] = excl;
        if (base + 1 < NN) off[base + 1] = excl + d0;
        if (base + 2 < NN) off[base + 2] = excl + d0 + d1;
        if (base + 3 < NN) off[base + 3] = excl + d0 + d1 + d2;
    }
    if (t == 255) bsum[bid] = woff + inc;
}

__global__ __launch_bounds__(64) void scan_spine(int* __restrict__ bsum,
                                                 int* __restrict__ off) {
    const int lane = threadIdx.x;
    int v = (lane < NB_SCAN) ? bsum[lane] : 0;
    int inc = v;
#pragma unroll
    for (int o = 1; o < 64; o <<= 1) {
        int u = __shfl_up(inc, o);
        if (lane >= o) inc += u;
    }
    if (lane < NB_SCAN) bsum[lane] = inc - v;
    if (lane == 63) off[NN] = inc;
}

__global__ __launch_bounds__(256) void scan_apply(const int* __restrict__ bsum,
                                                  int* __restrict__ off,
                                                  int* __restrict__ cur) {
    const int bid = blockIdx.x, t = threadIdx.x;
    const int boff = bsum[bid];
    const int base = bid * 1024 + t * 4;
    if (base + 3 < NN) {
        int4 v = *(const int4*)(off + base);
        v.x += boff; v.y += boff; v.z += boff; v.w += boff;
        *(int4*)(off + base) = v;
        *(int4*)(cur + base) = v;
    } else {
        for (int i = 0; i < 4; ++i)
            if (base + i < NN) {
                int v = off[base + i] + boff;
                off[base + i] = v;
                cur[base + i] = v;
            }
    }
}

// single random 2B write per edge (node ids < 65536)
__global__ __launch_bounds__(256) void scatter_kernel(const int* __restrict__ ei,
                                                      int* __restrict__ cur,
                                                      ushort* __restrict__ csr) {
    int i = blockIdx.x * 256 + threadIdx.x;
    if (i >= EP) return;
    int s, d;
    if (i < NN) { s = i; d = i; }           // self loop
    else { int e = i - NN; s = ei[e]; d = ei[EE + e]; }
    int pos = atomicAdd(&cur[d], 1);
    csr[pos] = (ushort)s;
}

// ---------------- merged weight prep (single launch, blockIdx-dispatched) ----------------
// blocks 0..15 : Bg  (W1stack sigma-packed fp16, 4096 frag-of-8)
// blocks 16..19: va  (folded alpha1 vectors, 1024)
// block  20    : vs/vd (folded alpha2 vectors, 256)
// blocks 21..26: Bp  (W2 sigma-packed fp16, 1536)
__global__ __launch_bounds__(256)
void prep_all(const float* __restrict__ W1, const float* __restrict__ a_src1,
              const float* __restrict__ a_dst1, const float* __restrict__ W2,
              const float* __restrict__ a_src2, const float* __restrict__ a_dst2,
              float* __restrict__ va, _Float16* __restrict__ Bg,
              float* __restrict__ vs, float* __restrict__ vd,
              _Float16* __restrict__ Bp) {
    const int bid = blockIdx.x, t = threadIdx.x;
    if (bid < 16) {
        // W1stack[kap = h*128+kx][c] = W1[kx][64h+c]
        int idx = bid * 256 + t;
        int l = idx & 63, kk = (idx >> 6) & 15, nb = idx >> 10;
        int c = 16 * nb + (l & 15);
        half8v v;
#pragma unroll
        for (int jj = 0; jj < 8; ++jj) {
            int kap = 32 * kk + 8 * (l >> 4) + jj;
            int kx = kap & 127, hh = kap >> 7;
            v[jj] = (_Float16)W1[(size_t)kx * 256 + hh * 64 + c];
        }
        *(half8v*)(Bg + (size_t)idx * 8) = v;
    } else if (bid < 20) {
        // va[v][k] = sum_c W1[k, 64*(v&3)+c] * a1[(v&3)][c]
        int idx = (bid - 16) * 256 + t;
        int v = idx >> 7, k = idx & 127, h = v & 3;
        const float* a = (v < 4) ? a_src1 : a_dst1;
        float s = 0.f;
        for (int c = 0; c < 64; ++c)
            s = fmaf(W1[(size_t)k * 256 + h * 64 + c], a[h * 64 + c], s);
        va[v * 128 + k] = s;
    } else if (bid == 20) {
        int h = t >> 6, k = t & 63;
        float s = 0.f, d = 0.f;
        for (int c = 0; c < NCLS; ++c) {
            float w = W2[(size_t)k * 160 + h * 40 + c];
            s = fmaf(w, a_src2[h * 40 + c], s);
            d = fmaf(w, a_dst2[h * 40 + c], d);
        }
        vs[t] = s; vd[t] = d;
    } else {
        int idx = (bid - 21) * 256 + t;
        if (idx >= 1536) return;
        int l = idx & 63, kk = (idx >> 6) & 7, n = idx >> 9;
        int c = 16 * n + (l & 15);
        half8v v;
#pragma unroll
        for (int j = 0; j < 8; ++j) {
            int kap = 32 * kk + 8 * (l >> 4) + j;
            float w = (c < NCLS) ? W2[(size_t)(kap & 63) * 160 + (kap >> 6) * 40 + c] : 0.f;
            v[j] = (_Float16)w;
        }
        *(half8v*)(Bp + (size_t)idx * 8) = v;
    }
}

// ---------------- x -> fp16 table + alpha1 logits (x . va) ----------------
__global__ __launch_bounds__(256)
void xprep_kernel(const float* __restrict__ x, const float* __restrict__ va,
                  _Float16* __restrict__ xh, float* __restrict__ as1,
                  float* __restrict__ ad1) {
    int n = (blockIdx.x * 256 + threadIdx.x) >> 6;
    if (n >= NN) return;
    int lane = threadIdx.x & 63;
    float2 xv = *(const float2*)(x + (size_t)n * 128 + lane * 2);
    half2v hx; hx.x = (_Float16)xv.x; hx.y = (_Float16)xv.y;
    *(half2v*)((char*)xh + ((size_t)n << 8) + lane * 4) = hx;
    float p[8];
#pragma unroll
    for (int v = 0; v < 8; ++v) {
        float2 c = *(const float2*)(va + v * 128 + lane * 2);
        p[v] = xv.x * c.x + xv.y * c.y;
    }
#pragma unroll
    for (int m = 1; m < 64; m <<= 1)
#pragma unroll
        for (int v = 0; v < 8; ++v) p[v] += __shfl_xor(p[v], m);
    if (lane == 0) {
        float4 s; s.x = p[0]; s.y = p[1]; s.z = p[2]; s.w = p[3];
        float4 d; d.x = p[4]; d.y = p[5]; d.z = p[6]; d.w = p[7];
        *(float4*)(as1 + n * 4) = s;
        *(float4*)(ad1 + n * 4) = d;
    }
}

// ---------------- layer-1 aggregation of RAW x (fp16), weights fused (R13) ----------------
// wave per node; lane holds x channels (2l, 2l+1) for all 4 heads.
// Weight block: lane (4*hC + eC) computes w(edge j+eC, head hC); 16 shfl / 4 edges.
__global__ __launch_bounds__(256)
void agg1x_kernel(const _Float16* __restrict__ xh, const float* __restrict__ as1,
                  const float* __restrict__ ad1, const int* __restrict__ off,
                  const ushort* __restrict__ csr, _Float16* __restrict__ G1) {
    int n = (blockIdx.x * 256 + threadIdx.x) >> 6;
    if (n >= NN) return;
    const int lane = threadIdx.x & 63;
    const int hC = (lane >> 2) & 3, eC = lane & 3;
    const float advC = ad1[n * 4 + hC];
    const char* xb = (const char*)xh;
    const uint lb = (uint)lane * 4u;
    int e0 = off[n], e1 = off[n + 1];
    f32x2 g0 = {0.f, 0.f}, g1 = {0.f, 0.f}, g2 = {0.f, 0.f}, g3 = {0.f, 0.f};
    f32x2 d01 = {0.f, 0.f}, d23 = {0.f, 0.f};
    int j = e0;
    for (; j + 4 <= e1; j += 4) {
        int s0 = csr[j], s1 = csr[j + 1], s2 = csr[j + 2], s3 = csr[j + 3];
        int sC = csr[j + eC];
        float wX = lrelu_exp(as1[sC * 4 + hC] + advC);
        half2v x0 = *(const half2v*)(xb + (((uint)s0 << 8) + lb));
        half2v x1 = *(const half2v*)(xb + (((uint)s1 << 8) + lb));
        half2v x2 = *(const half2v*)(xb + (((uint)s2 << 8) + lb));
        half2v x3 = *(const half2v*)(xb + (((uint)s3 << 8) + lb));
        float4 wA, wB, wC4, wD;
        wA.x = __shfl(wX, 0);  wA.y = __shfl(wX, 4);  wA.z = __shfl(wX, 8);  wA.w = __shfl(wX, 12);
        wB.x = __shfl(wX, 1);  wB.y = __shfl(wX, 5);  wB.z = __shfl(wX, 9);  wB.w = __shfl(wX, 13);
        wC4.x = __shfl(wX, 2); wC4.y = __shfl(wX, 6); wC4.z = __shfl(wX, 10); wC4.w = __shfl(wX, 14);
        wD.x = __shfl(wX, 3);  wD.y = __shfl(wX, 7);  wD.z = __shfl(wX, 11); wD.w = __shfl(wX, 15);
        f32x2 f0 = {(float)x0.x, (float)x0.y};
        f32x2 f1 = {(float)x1.x, (float)x1.y};
        f32x2 f2 = {(float)x2.x, (float)x2.y};
        f32x2 f3 = {(float)x3.x, (float)x3.y};
        g0 = __builtin_elementwise_fma((f32x2){wA.x, wA.x}, f0, g0);
        g1 = __builtin_elementwise_fma((f32x2){wA.y, wA.y}, f0, g1);
        g2 = __builtin_elementwise_fma((f32x2){wA.z, wA.z}, f0, g2);
        g3 = __builtin_elementwise_fma((f32x2){wA.w, wA.w}, f0, g3);
        d01 += (f32x2){wA.x, wA.y}; d23 += (f32x2){wA.z, wA.w};
        g0 = __builtin_elementwise_fma((f32x2){wB.x, wB.x}, f1, g0);
        g1 = __builtin_elementwise_fma((f32x2){wB.y, wB.y}, f1, g1);
        g2 = __builtin_elementwise_fma((f32x2){wB.z, wB.z}, f1, g2);
        g3 = __builtin_elementwise_fma((f32x2){wB.w, wB.w}, f1, g3);
        d01 += (f32x2){wB.x, wB.y}; d23 += (f32x2){wB.z, wB.w};
        g0 = __builtin_elementwise_fma((f32x2){wC4.x, wC4.x}, f2, g0);
        g1 = __builtin_elementwise_fma((f32x2){wC4.y, wC4.y}, f2, g1);
        g2 = __builtin_elementwise_fma((f32x2){wC4.z, wC4.z}, f2, g2);
        g3 = __builtin_elementwise_fma((f32x2){wC4.w, wC4.w}, f2, g3);
        d01 += (f32x2){wC4.x, wC4.y}; d23 += (f32x2){wC4.z, wC4.w};
        g0 = __builtin_elementwise_fma((f32x2){wD.x, wD.x}, f3, g0);
        g1 = __builtin_elementwise_fma((f32x2){wD.y, wD.y}, f3, g1);
        g2 = __builtin_elementwise_fma((f32x2){wD.z, wD.z}, f3, g2);
        g3 = __builtin_elementwise_fma((f32x2){wD.w, wD.w}, f3, g3);
        d01 += (f32x2){wD.x, wD.y}; d23 += (f32x2){wD.z, wD.w};
    }
    for (; j < e1; ++j) {
        int s = csr[j];
        half2v xv = *(const half2v*)(xb + (((uint)s << 8) + lb));
        float4 av = *(const float4*)(as1 + s * 4);
        float4 dv;   // per-lane full weights (tail <=3 edges)
        dv.x = lrelu_exp(av.x + __shfl(advC, 0));
        dv.y = lrelu_exp(av.y + __shfl(advC, 4));
        dv.z = lrelu_exp(av.z + __shfl(advC, 8));
        dv.w = lrelu_exp(av.w + __shfl(advC, 12));
        f32x2 f0 = {(float)xv.x, (float)xv.y};
        g0 = __builtin_elementwise_fma((f32x2){dv.x, dv.x}, f0, g0);
        g1 = __builtin_elementwise_fma((f32x2){dv.y, dv.y}, f0, g1);
        g2 = __builtin_elementwise_fma((f32x2){dv.z, dv.z}, f0, g2);
        g3 = __builtin_elementwise_fma((f32x2){dv.w, dv.w}, f0, g3);
        d01 += (f32x2){dv.x, dv.y}; d23 += (f32x2){dv.z, dv.w};
    }
    float i0 = 1.f / (d01.x + 1e-16f);
    float i1 = 1.f / (d01.y + 1e-16f);
    float i2 = 1.f / (d23.x + 1e-16f);
    float i3 = 1.f / (d23.y + 1e-16f);
    char* gb = (char*)G1 + ((size_t)n << 10);
    half2v o;
    o.x = (_Float16)(g0.x * i0); o.y = (_Float16)(g0.y * i0);
    *(half2v*)(gb + 0   + lb) = o;
    o.x = (_Float16)(g1.x * i1); o.y = (_Float16)(g1.y * i1);
    *(half2v*)(gb + 256 + lb) = o;
    o.x = (_Float16)(g2.x * i2); o.y = (_Float16)(g2.y * i2);
    *(half2v*)(gb + 512 + lb) = o;
    o.x = (_Float16)(g3.x * i3); o.y = (_Float16)(g3.y * i3);
    *(half2v*)(gb + 768 + lb) = o;
}

// ---------------- gemm_g1: h1o[N,64] = relu(0.25*G1[N,512]@W1stack + b1); + logits ----------------
__global__ __launch_bounds__(256)
void gemm_g1(const _Float16* __restrict__ G1, const _Float16* __restrict__ Bg,
             const float* __restrict__ b1, const float* __restrict__ vs,
             const float* __restrict__ vd, _Float16* __restrict__ h1of,
             float* __restrict__ as2, float* __restrict__ ad2, int M) {
    __shared__ _Float16 Al[64 * 512];   // 64 KB
    const int t    = threadIdx.x;
    const int row0 = blockIdx.x * 64;

#pragma unroll
    for (int i = 0; i < 16; ++i) {
        int chunk = i * 256 + t;
        int r = chunk >> 6, c8 = (chunk & 63) * 8;
        int rg = row0 + r; if (rg >= M) rg = M - 1;
        half8v v = *(const half8v*)(G1 + ((size_t)rg << 9) + c8);
        int byte = (r * 1024 + c8 * 2) ^ ((r & 7) << 4);
        *(half8v*)((char*)Al + byte) = v;
    }
    __syncthreads();

    const int lane = t & 63, w = t >> 6;
    const int g = lane >> 4, cc = lane & 15;

    half8v a[16];
#pragma unroll
    for (int kk = 0; kk < 16; ++kk) {
        int r = 16 * w + cc;
        int byte = (r * 1024 + (32 * kk + 8 * g) * 2) ^ ((r & 7) << 4);
        a[kk] = *(const half8v*)((const char*)Al + byte);
    }

    f32x4 acc[4];
#pragma unroll
    for (int nb = 0; nb < 4; ++nb)
#pragma unroll
        for (int i = 0; i < 4; ++i) acc[nb][i] = 0.f;

#pragma unroll
    for (int nb = 0; nb < 4; ++nb)
#pragma unroll
        for (int kk = 0; kk < 16; ++kk) {
            half8v b = *(const half8v*)(Bg + ((size_t)(nb * 16 + kk) * 64 + lane) * 8);
            acc[nb] = __builtin_amdgcn_mfma_f32_16x16x32_f16(a[kk], b, acc[nb], 0, 0, 0);
        }

#pragma unroll
    for (int i = 0; i < 4; ++i) {
        int r = row0 + 16 * w + 4 * g + i;
        float o[4];
#pragma unroll
        for (int nb = 0; nb < 4; ++nb)
            o[nb] = fmaxf(0.25f * acc[nb][i] + b1[16 * nb + cc], 0.f);
        bool ok = (r < M) && !(cc & 1);
#pragma unroll
        for (int nb = 0; nb < 4; ++nb) {
            float v1 = __shfl_xor(o[nb], 1);
            if (ok) {
                half2v h2; h2.x = (_Float16)o[nb]; h2.y = (_Float16)v1;
                *(half2v*)(h1of + (size_t)r * 64 + 16 * nb + cc) = h2;
            }
        }
#pragma unroll
        for (int h = 0; h < 4; ++h) {
            float s = 0.f, d = 0.f;
#pragma unroll
            for (int nb = 0; nb < 4; ++nb) {
                s = fmaf(o[nb], vs[h * 64 + 16 * nb + cc], s);
                d = fmaf(o[nb], vd[h * 64 + 16 * nb + cc], d);
            }
#pragma unroll
            for (int m = 1; m <= 8; m <<= 1) {
                s += __shfl_xor(s, m);
                d += __shfl_xor(d, m);
            }
            if (cc == 0 && r < M) { as2[r * 4 + h] = s; ad2[r * 4 + h] = d; }
        }
    }
}

// ---------------- layer-2 aggregation: gather raw h1o (fp16), weights fused (R13) ----------------
__global__ __launch_bounds__(256)
void agg2_kernel(const _Float16* __restrict__ h1of, const float* __restrict__ as2,
                 const float* __restrict__ ad2, const int* __restrict__ off,
                 const ushort* __restrict__ csr, _Float16* __restrict__ g2h) {
    int n = (blockIdx.x * 256 + threadIdx.x) >> 6;
    if (n >= NN) return;
    const int lane = threadIdx.x & 63;
    const int hd = lane >> 4, q = lane & 15;
    const int hC = (lane >> 2) & 3, eC = lane & 3;
    const float advC = ad2[n * 4 + hC];
    const char* hb = (const char*)h1of;
    const uint qB = (uint)q * 8u;
    int e0 = off[n], e1 = off[n + 1];
    f32x2 a01 = {0.f, 0.f}, a23 = {0.f, 0.f};
    float den = 0.f;
    int j = e0;
    for (; j + 4 <= e1; j += 4) {
        int s0 = csr[j], s1 = csr[j + 1], s2 = csr[j + 2], s3 = csr[j + 3];
        int sC = csr[j + eC];
        float wX = lrelu_exp(as2[sC * 4 + hC] + advC);
        half4v v0 = *(const half4v*)(hb + (((uint)s0 << 7) + qB));
        half4v v1 = *(const half4v*)(hb + (((uint)s1 << 7) + qB));
        half4v v2 = *(const half4v*)(hb + (((uint)s2 << 7) + qB));
        half4v v3 = *(const half4v*)(hb + (((uint)s3 << 7) + qB));
        int sb = hd << 2;
        float w0 = __shfl(wX, sb + 0);
        float w1 = __shfl(wX, sb + 1);
        float w2v = __shfl(wX, sb + 2);
        float w3 = __shfl(wX, sb + 3);
        den += (w0 + w1) + (w2v + w3);
        a01 = __builtin_elementwise_fma((f32x2){w0, w0}, (f32x2){(float)v0.x, (float)v0.y}, a01);
        a23 = __builtin_elementwise_fma((f32x2){w0, w0}, (f32x2){(float)v0.z, (float)v0.w}, a23);
        a01 = __builtin_elementwise_fma((f32x2){w1, w1}, (f32x2){(float)v1.x, (float)v1.y}, a01);
        a23 = __builtin_elementwise_fma((f32x2){w1, w1}, (f32x2){(float)v1.z, (float)v1.w}, a23);
        a01 = __builtin_elementwise_fma((f32x2){w2v, w2v}, (f32x2){(float)v2.x, (float)v2.y}, a01);
        a23 = __builtin_elementwise_fma((f32x2){w2v, w2v}, (f32x2){(float)v2.z, (float)v2.w}, a23);
        a01 = __builtin_elementwise_fma((f32x2){w3, w3}, (f32x2){(float)v3.x, (float)v3.y}, a01);
        a23 = __builtin_elementwise_fma((f32x2){w3, w3}, (f32x2){(float)v3.z, (float)v3.w}, a23);
    }
    for (; j < e1; ++j) {
        int s = csr[j];
        half4v hv = *(const half4v*)(hb + (((uint)s << 7) + qB));
        float w = lrelu_exp(as2[s * 4 + hd] + ad2[n * 4 + hd]);
        den += w;
        a01 = __builtin_elementwise_fma((f32x2){w, w}, (f32x2){(float)hv.x, (float)hv.y}, a01);
        a23 = __builtin_elementwise_fma((f32x2){w, w}, (f32x2){(float)hv.z, (float)hv.w}, a23);
    }
    float inv = 1.f / (den + 1e-16f);
    half4v g;
    g.x = (_Float16)(a01.x * inv); g.y = (_Float16)(a01.y * inv);
    g.z = (_Float16)(a23.x * inv); g.w = (_Float16)(a23.y * inv);
    *(half4v*)(g2h + (size_t)n * 256 + hd * 64 + q * 4) = g;
}

// ---------------- output GEMM: out = 0.25*g2[N,256]@Bp + b2 ----------------
__global__ __launch_bounds__(256)
void gemm_out(const _Float16* __restrict__ g2h, const _Float16* __restrict__ Bp,
              const float* __restrict__ b2, float* __restrict__ out, int M) {
    __shared__ _Float16 Al[128 * 256];   // 64 KB
    const int t    = threadIdx.x;
    const int row0 = blockIdx.x * 128;

#pragma unroll
    for (int i = 0; i < 16; ++i) {
        int chunk = i * 256 + t;
        int r = chunk >> 5, c = (chunk & 31) * 8;
        int rg = row0 + r; if (rg >= M) rg = M - 1;
        half8v v = *(const half8v*)(g2h + (size_t)rg * 256 + c);
        int byte = (r * 512 + c * 2) ^ ((r & 7) << 4);
        *(half8v*)((char*)Al + byte) = v;
    }
    __syncthreads();

    const int lane = t & 63, w = t >> 6;
    const int g = lane >> 4, cc = lane & 15;

    half8v a[2][8];
#pragma unroll
    for (int m = 0; m < 2; ++m)
#pragma unroll
        for (int kk = 0; kk < 8; ++kk) {
            int r = 32 * w + 16 * m + cc;
            int byte = (r * 512 + (32 * kk + 8 * g) * 2) ^ ((r & 7) << 4);
            a[m][kk] = *(const half8v*)((const char*)Al + byte);
        }

    f32x4 acc[2][3];
#pragma unroll
    for (int m = 0; m < 2; ++m)
#pragma unroll
        for (int n = 0; n < 3; ++n)
#pragma unroll
            for (int i = 0; i < 4; ++i) acc[m][n][i] = 0.f;

#pragma unroll
    for (int n = 0; n < 3; ++n)
#pragma unroll
        for (int kk = 0; kk < 8; ++kk) {
            half8v b = *(const half8v*)(Bp + ((size_t)(n * 8 + kk) * 64 + lane) * 8);
            acc[0][n] = __builtin_amdgcn_mfma_f32_16x16x32_f16(a[0][kk], b, acc[0][n], 0, 0, 0);
            acc[1][n] = __builtin_amdgcn_mfma_f32_16x16x32_f16(a[1][kk], b, acc[1][n], 0, 0, 0);
        }

#pragma unroll
    for (int m = 0; m < 2; ++m)
#pragma unroll
        for (int i = 0; i < 4; ++i) {
            int r = row0 + 32 * w + 16 * m + 4 * g + i;
            if (r < M) {
#pragma unroll
                for (int n = 0; n < 3; ++n) {
                    int c = 16 * n + cc;
                    if (c < NCLS)
                        out[(size_t)r * 40 + c] = 0.25f * acc[m][n][i] + b2[c];
                }
            }
        }
}

// ---------------- launch ----------------

extern "C" void kernel_launch(void* const* d_in, const int* in_sizes, int n_in,
                              void* d_out, int out_size, void* d_ws, size_t ws_size,
                              hipStream_t stream) {
    const float* x      = (const float*)d_in[0];
    const int*   ei     = (const int*)  d_in[1];
    const float* W1     = (const float*)d_in[2];
    const float* a_src1 = (const float*)d_in[3];
    const float* a_dst1 = (const float*)d_in[4];
    const float* b1     = (const float*)d_in[5];
    const float* W2     = (const float*)d_in[6];
    const float* a_src2 = (const float*)d_in[7];
    const float* a_dst2 = (const float*)d_in[8];
    const float* b2     = (const float*)d_in[9];
    float* out = (float*)d_out;

    char* p = (char*)d_ws;
    auto alloc = [&](size_t bytes) {
        void* r = (void*)p;
        p += (bytes + 255) & ~(size_t)255;
        return r;
    };
    int*       deg  = (int*)alloc((size_t)NN * 4);
    int*       off  = (int*)alloc((size_t)(NN + 1) * 4);
    int*       cur  = (int*)alloc((size_t)NN * 4);
    int*       bsum = (int*)alloc((size_t)NB_SCAN * 4);
    ushort*    csr  = (ushort*)alloc((size_t)EP * 2);
    float*     va   = (float*)alloc((size_t)1024 * 4);
    _Float16*  Bg   = (_Float16*)alloc((size_t)4096 * 8 * 2);
    float*     vs   = (float*)alloc((size_t)256 * 4);
    float*     vd   = (float*)alloc((size_t)256 * 4);
    _Float16*  Bp   = (_Float16*)alloc((size_t)1536 * 8 * 2);
    _Float16*  xh   = (_Float16*)alloc((size_t)NN * 128 * 2);   // 12.8 MB gather table
    float*     as1  = (float*)alloc((size_t)NN * 4 * 4);
    float*     ad1  = (float*)alloc((size_t)NN * 4 * 4);
    _Float16*  G1   = (_Float16*)alloc((size_t)NN * 512 * 2);   // 51.2 MB; reused as g2h
    _Float16*  h1of = (_Float16*)alloc((size_t)NN * 64 * 2);    // 6.4 MB gather table
    float*     as2  = (float*)alloc((size_t)NN * 4 * 4);
    float*     ad2  = (float*)alloc((size_t)NN * 4 * 4);
    _Float16*  g2h  = G1;   // G1 dead after gemm_g1

    // CSR over dst (shared by both layers)
    hipMemsetAsync(deg, 0, (size_t)NN * 4, stream);
    hist_kernel<<<(EE + 255) / 256, 256, 0, stream>>>(ei, deg);
    scan_blocks<<<NB_SCAN, 256, 0, stream>>>(deg, off, bsum);
    scan_spine<<<1, 64, 0, stream>>>(bsum, off);
    scan_apply<<<NB_SCAN, 256, 0, stream>>>(bsum, off, cur);
    scatter_kernel<<<(EP + 255) / 256, 256, 0, stream>>>(ei, cur, csr);

    // merged weight prep (single launch)
    prep_all<<<27, 256, 0, stream>>>(W1, a_src1, a_dst1, W2, a_src2, a_dst2,
                                     va, Bg, vs, vd, Bp);

    // layer 1 (weights fused into aggregation)
    xprep_kernel<<<(NN + 3) / 4, 256, 0, stream>>>(x, va, xh, as1, ad1);
    agg1x_kernel<<<(NN + 3) / 4, 256, 0, stream>>>(xh, as1, ad1, off, csr, G1);
    gemm_g1<<<(NN + 63) / 64, 256, 0, stream>>>(G1, Bg, b1, vs, vd, h1of, as2, ad2, NN);

    // layer 2 (weights fused into aggregation)
    agg2_kernel<<<(NN + 3) / 4, 256, 0, stream>>>(h1of, as2, ad2, off, csr, g2h);
    gemm_out<<<(NN + 127) / 128, 256, 0, stream>>>(g2h, Bp, b2, out, NN);
}